// Round 5
// baseline (471.208 us; speedup 1.0000x reference)
//
#include <hip/hip_runtime.h>
#include <hip/hip_bf16.h>
#include <math.h>

// ---------------- problem constants ----------------
#define NB    32          // graphs
#define NPG   512         // nodes per graph
#define NTOT  (NB*NPG)    // 16384
#define EPG   4096
#define ETOT  (NB*EPG)    // 131072
#define K1    308
#define K2    185
#define N2    (NB*K1)     // 9856
#define N3    (NB*K2)     // 5920
#define SLOPE 0.2f

typedef _Float16 f16;
typedef f16   f16x8 __attribute__((ext_vector_type(8)));
typedef float f32x4 __attribute__((ext_vector_type(4)));

// W pre-scale (power of 2, exact) keeps lo-split in fp16 normal range
#define WSCALE 512.0f
#define WINV   (1.0f/512.0f)

// monotone float <-> uint encoding (total order preserved)
__device__ __forceinline__ unsigned enc_f(float v) {
    unsigned u = __float_as_uint(v);
    return (u & 0x80000000u) ? ~u : (u | 0x80000000u);
}
__device__ __forceinline__ float dec_f(unsigned e) {
    return (e & 0x80000000u) ? __uint_as_float(e ^ 0x80000000u) : __uint_as_float(~e);
}

// async global->LDS, 16B per lane, wave-uniform LDS base
__device__ __forceinline__ void gll16(const void* g, void* l)
{
    __builtin_amdgcn_global_load_lds(
        (const __attribute__((address_space(1))) unsigned int*)g,
        (__attribute__((address_space(3))) unsigned int*)l, 16, 0, 0);
}

// ---------------- split fp32 -> (hi,lo) fp16 ----------------
__global__ __launch_bounds__(256) void split_a(const float* __restrict__ A,
                                               f16* __restrict__ Ah, f16* __restrict__ Al,
                                               int n8)
{
    int i = blockIdx.x * 256 + threadIdx.x;   // 8 floats per thread
    if (i >= n8) return;
    const float4* p = (const float4*)(A + (size_t)i * 8);
    float4 v0 = p[0], v1 = p[1];
    float v[8] = {v0.x, v0.y, v0.z, v0.w, v1.x, v1.y, v1.z, v1.w};
    f16x8 h, l;
#pragma unroll
    for (int j = 0; j < 8; ++j) {
        f16 hh = (f16)v[j];
        h[j] = hh;
        l[j] = (f16)(v[j] - (float)hh);
    }
    *(f16x8*)(Ah + (size_t)i * 8) = h;
    *(f16x8*)(Al + (size_t)i * 8) = l;
}

// ---------------- W prep: concat L|R, transpose to [1024][K], scale, split ----------------
__global__ __launch_bounds__(256) void prep_w(const float* __restrict__ WL,
                                              const float* __restrict__ WR,
                                              f16* __restrict__ Wh, f16* __restrict__ Wlo,
                                              int K)
{
    __shared__ float t[32][33];
    int bk = blockIdx.x;          // k tile (K/32)
    int bn = blockIdx.y;          // n tile (32 tiles of 32 over 1024)
    int tx = threadIdx.x & 31, ty = threadIdx.x >> 5;   // 32 x 8
    const float* Wsrc = (bn < 16) ? WL : WR;
    int ncol = bn * 32 - (bn < 16 ? 0 : 512) + tx;
#pragma unroll
    for (int q = 0; q < 4; ++q) {
        int kk = bk * 32 + ty + q * 8;
        t[ty + q * 8][tx] = Wsrc[(size_t)kk * 512 + ncol];
    }
    __syncthreads();
#pragma unroll
    for (int q = 0; q < 4; ++q) {
        int n = bn * 32 + ty + q * 8;
        int k = bk * 32 + tx;
        float v = t[tx][ty + q * 8] * WSCALE;
        f16 h = (f16)v;
        Wh [(size_t)n * K + k] = h;
        Wlo[(size_t)n * K + k] = (f16)(v - (float)h);
    }
}

// ---------------- split-fp16 MFMA GEMM: depth-2 pipeline, counted vmcnt ----------------
// C[M,1024] = (Ah+Al)[M,K] @ (Wh+Wlo)^T[K,1024] * WINV + bias(l|r)
// block: 256 thr / 4 waves; tile 128x128; BK=32; wave w owns 64x64 quadrant.
// 3 LDS buffers; stage tile t+2 during step t; wait vmcnt(8) (NOT 0) per step.
__global__ __launch_bounds__(256) void gemm_split(
    const f16* __restrict__ Ah, const f16* __restrict__ Al,
    const f16* __restrict__ Bh, const f16* __restrict__ Bl,
    const float* __restrict__ bias_l, const float* __restrict__ bias_r,
    float* __restrict__ C, int M, int K)
{
    __shared__ f16 sm[3][4][4][128][8];   // [buf][mat: Ah,Al,Bh,Bl][kblk][row][8k] = 96 KB
    const int Nn = 1024;
    int tid = threadIdx.x;
    int wave = tid >> 6, lane = tid & 63;
    int row0 = blockIdx.y * 128, col0 = blockIdx.x * 128;

    const f16* base = (wave == 0) ? Ah : (wave == 1) ? Al : (wave == 2) ? Bh : Bl;
    int rc0 = (wave < 2) ? row0 : col0;

    int wr = wave >> 1, wc = wave & 1;
    int r16 = lane & 15, kb = lane >> 4;

    const int nt = K >> 5;   // K/32 tiles

    // stage K-tile t into buffer buf (wave w loads matrix w: 8 chunks of 64 rows x 8 k)
    const f16* srow = base + (size_t)(rc0 + lane) * K;   // lane's row base
    auto stage = [&](int buf, int t) {
#pragma unroll
        for (int i = 0; i < 8; ++i) {
            int kblk = i >> 1, rh = i & 1;
            const f16* src = srow + (size_t)(rh * 64) * K + t * 32 + kblk * 8;
            gll16(src, &sm[buf][wave][kblk][rh * 64][0]);
        }
    };

    f32x4 acc[4][4] = {};
    stage(0, 0);
    if (nt > 1) stage(1, 1);

    for (int t = 0; t < nt; ++t) {
        // wait for OWN share of tile t: everything except the newest 8 loads (tile t+1).
        if (t < nt - 1) asm volatile("s_waitcnt vmcnt(8)" ::: "memory");
        else            asm volatile("s_waitcnt vmcnt(0)" ::: "memory");
        __builtin_amdgcn_s_barrier();   // publish all waves' tile-t stores; all done reading t-1

        if (t + 2 < nt) stage((t + 2) % 3, t + 2);   // overwrites buf[(t-1)%3] (safe per barrier)

        int cb = t % 3;
        f16x8 a_h[4], a_l[4], b_h[4], b_l[4];
#pragma unroll
        for (int m = 0; m < 4; ++m) {
            a_h[m] = *(const f16x8*)&sm[cb][0][kb][wr * 64 + m * 16 + r16][0];
            a_l[m] = *(const f16x8*)&sm[cb][1][kb][wr * 64 + m * 16 + r16][0];
        }
#pragma unroll
        for (int n = 0; n < 4; ++n) {
            b_h[n] = *(const f16x8*)&sm[cb][2][kb][wc * 64 + n * 16 + r16][0];
            b_l[n] = *(const f16x8*)&sm[cb][3][kb][wc * 64 + n * 16 + r16][0];
        }
        // term-major: 16 independent MFMAs between accumulator reuses;
        // per-acc order stays hh -> hl -> lh (bit-identical accumulation order)
#pragma unroll
        for (int m = 0; m < 4; ++m)
#pragma unroll
            for (int n = 0; n < 4; ++n)
                acc[m][n] = __builtin_amdgcn_mfma_f32_16x16x32_f16(a_h[m], b_h[n], acc[m][n], 0, 0, 0);
#pragma unroll
        for (int m = 0; m < 4; ++m)
#pragma unroll
            for (int n = 0; n < 4; ++n)
                acc[m][n] = __builtin_amdgcn_mfma_f32_16x16x32_f16(a_h[m], b_l[n], acc[m][n], 0, 0, 0);
#pragma unroll
        for (int m = 0; m < 4; ++m)
#pragma unroll
            for (int n = 0; n < 4; ++n)
                acc[m][n] = __builtin_amdgcn_mfma_f32_16x16x32_f16(a_l[m], b_h[n], acc[m][n], 0, 0, 0);
        // NO end-of-step barrier: next iteration's vmcnt+barrier provides it.
    }
    // epilogue: C/D frag: col = lane&15, row = (lane>>4)*4 + j
#pragma unroll
    for (int m = 0; m < 4; ++m)
#pragma unroll
        for (int n = 0; n < 4; ++n) {
            int cc = col0 + wc * 64 + n * 16 + r16;
            float b = (cc < 512) ? bias_l[cc] : bias_r[cc - 512];
#pragma unroll
            for (int j = 0; j < 4; ++j) {
                int rr = row0 + wr * 64 + m * 16 + kb * 4 + j;
                C[(size_t)rr * Nn + cc] = acc[m][n][j] * WINV + b;
            }
        }
}

// ---------------- CSR build ----------------
__global__ void count_edges(const int* __restrict__ dst, int E_in, int* __restrict__ cnt)
{
    int e = blockIdx.x * blockDim.x + threadIdx.x;
    if (e < E_in) atomicAdd(&cnt[dst[e]], 1);
}

__global__ void fill_edges(const int* __restrict__ src, const int* __restrict__ dst,
                           int E_in, int* __restrict__ next, int* __restrict__ csr)
{
    int e = blockIdx.x * blockDim.x + threadIdx.x;
    if (e < E_in) {
        int p = atomicAdd(&next[dst[e]], 1);
        csr[p] = src[e];
    }
}

__global__ __launch_bounds__(1024) void scan_excl(const int* __restrict__ cnt, int n,
                                                  int* __restrict__ off, int* __restrict__ next)
{
    __shared__ int bsum[1024];
    int t = threadIdx.x;
    int chunk = (n + 1023) >> 10;
    int lo = t * chunk, hi = min(n, lo + chunk);
    int s = 0;
    for (int i = lo; i < hi; ++i) s += cnt[i];
    bsum[t] = s;
    __syncthreads();
    for (int d = 1; d < 1024; d <<= 1) {
        int v = (t >= d) ? bsum[t - d] : 0;
        __syncthreads();
        bsum[t] += v;
        __syncthreads();
    }
    int run = t ? bsum[t - 1] : 0;
    for (int i = lo; i < hi; ++i) { off[i] = run; next[i] = run; run += cnt[i]; }
    if (t == 1023) off[n] = bsum[1023];
}

__global__ void remap_edges(const int* __restrict__ src, const int* __restrict__ dst,
                            int E_in, const int* __restrict__ nmap,
                            int* __restrict__ es2, int* __restrict__ ed2,
                            int* __restrict__ ec2, int* __restrict__ cnt2)
{
    int e = blockIdx.x * blockDim.x + threadIdx.x;
    if (e >= E_in) return;
    int ns = nmap[src[e]], nd = nmap[dst[e]];
    if (ns >= 0 && nd >= 0) {
        int pos = atomicAdd(ec2, 1);
        es2[pos] = ns; ed2[pos] = nd;
        atomicAdd(&cnt2[nd], 1);
    }
}

__global__ void fill_edges_dyn(const int* __restrict__ es, const int* __restrict__ ed,
                               const int* __restrict__ ec, int* __restrict__ next,
                               int* __restrict__ csr)
{
    int e = blockIdx.x * blockDim.x + threadIdx.x;
    if (e < *ec) {
        int p = atomicAdd(&next[ed[e]], 1);
        csr[p] = es[e];
    }
}

// ---------------- GATv2 aggregation: one wave per dst node ----------------
__global__ __launch_bounds__(256) void gatv2_agg(
    const float* __restrict__ XL, const float* __restrict__ XR, int ldx,
    const int* __restrict__ csr_src, const int* __restrict__ off,
    const float* __restrict__ att, const float* __restrict__ bias,
    float* __restrict__ out, int n)
{
    int nwg = gridDim.x;
    int q = nwg >> 3;
    int swz = (blockIdx.x & 7) * q + (blockIdx.x >> 3);
    int wid = swz * 4 + (threadIdx.x >> 6);
    int lane = threadIdx.x & 63;
    if (wid >= n) return;
    const int f0 = lane * 8;
    float xr[8], atv[8], acc[8];
    {
        float4 r0 = *(const float4*)&XR[(size_t)wid * ldx + f0];
        float4 r1 = *(const float4*)&XR[(size_t)wid * ldx + f0 + 4];
        xr[0]=r0.x; xr[1]=r0.y; xr[2]=r0.z; xr[3]=r0.w;
        xr[4]=r1.x; xr[5]=r1.y; xr[6]=r1.z; xr[7]=r1.w;
        float4 t0 = *(const float4*)&att[f0];
        float4 t1 = *(const float4*)&att[f0 + 4];
        atv[0]=t0.x; atv[1]=t0.y; atv[2]=t0.z; atv[3]=t0.w;
        atv[4]=t1.x; atv[5]=t1.y; atv[6]=t1.z; atv[7]=t1.w;
#pragma unroll
        for (int j = 0; j < 8; ++j) acc[j] = 0.f;
    }
    float m = -INFINITY, ssum = 0.f;
    int e0 = off[wid], e1 = off[wid + 1];
    for (int e = e0 - 1; e < e1; ++e) {
        int s = (e < e0) ? wid : csr_src[e];
        float xl[8], part = 0.f;
        float4 l0 = *(const float4*)&XL[(size_t)s * ldx + f0];
        float4 l1 = *(const float4*)&XL[(size_t)s * ldx + f0 + 4];
        xl[0]=l0.x; xl[1]=l0.y; xl[2]=l0.z; xl[3]=l0.w;
        xl[4]=l1.x; xl[5]=l1.y; xl[6]=l1.z; xl[7]=l1.w;
#pragma unroll
        for (int j = 0; j < 8; ++j) {
            float v = xl[j] + xr[j];
            v = (v > 0.f) ? v : SLOPE * v;
            part += v * atv[j];
        }
        part += __shfl_xor(part, 1);
        part += __shfl_xor(part, 2);
        part += __shfl_xor(part, 4);
        part += __shfl_xor(part, 8);
        float mn = fmaxf(m, part);
        float scale = __expf(m - mn);
        float p = __expf(part - mn);
        ssum = ssum * scale + p;
#pragma unroll
        for (int j = 0; j < 8; ++j) acc[j] = acc[j] * scale + p * xl[j];
        m = mn;
    }
    float inv = 1.f / ssum;
#pragma unroll
    for (int j = 0; j < 8; ++j) {
        float v = acc[j] * inv;
        v += __shfl_xor(v, 16);
        v += __shfl_xor(v, 32);
        if (lane < 16) {
            int c = lane * 8 + j;
            float r = 0.25f * v + bias[c];
            out[(size_t)wid * 128 + c] = fmaxf(r, 0.f);
        }
    }
}

// ---------------- SAGE pooling score ----------------
__global__ __launch_bounds__(256) void sage_score(
    const float* __restrict__ X, const int* __restrict__ csr_src,
    const int* __restrict__ off, const float* __restrict__ Wn,
    const float* __restrict__ Wr, const float* __restrict__ bs,
    float* __restrict__ score, int n)
{
    int wid = (blockIdx.x * blockDim.x + threadIdx.x) >> 6;
    int lane = threadIdx.x & 63;
    if (wid >= n) return;
    int c0 = lane * 2;
    int e0 = off[wid], e1 = off[wid + 1];
    float a0 = 0.f, a1 = 0.f;
    for (int e = e0; e < e1; ++e) {
        int s = csr_src[e];
        float2 v = *(const float2*)&X[(size_t)s * 128 + c0];
        a0 += v.x; a1 += v.y;
    }
    float inv = 1.f / fmaxf((float)(e1 - e0), 1.f);
    float2 xv = *(const float2*)&X[(size_t)wid * 128 + c0];
    float part = a0 * inv * Wn[c0] + a1 * inv * Wn[c0 + 1] + xv.x * Wr[c0] + xv.y * Wr[c0 + 1];
#pragma unroll
    for (int sh = 1; sh < 64; sh <<= 1) part += __shfl_xor(part, sh);
    if (lane == 0) score[wid] = part + bs[0];
}

// ---------------- SAGPooling top-k (exact jax.lax.top_k rank) ----------------
__global__ __launch_bounds__(512) void pool_rank(const float* __restrict__ score,
                                                 int npg, int k, int* __restrict__ nmap)
{
    __shared__ float s[512];
    int b = blockIdx.x, t = threadIdx.x;
    const float* sc = score + (size_t)b * npg;
    if (t < npg) s[t] = sc[t];
    __syncthreads();
    if (t < npg) {
        float mine = s[t];
        int rank = 0;
        for (int j = 0; j < npg; ++j) {
            float v = s[j];
            rank += (v > mine) || (v == mine && j < t);
        }
        nmap[(size_t)b * npg + t] = (rank < k) ? (b * k + rank) : -1;
    }
}

// gather + tanh gate; optionally emit fp16 split for the next GEMM
__global__ void pool_gather(const float* __restrict__ X, const float* __restrict__ score,
                            const int* __restrict__ nmap, float* __restrict__ Xn,
                            f16* __restrict__ Xh, f16* __restrict__ Xl)
{
    int i = blockIdx.x, c = threadIdx.x;  // 128 threads
    int nid = nmap[i];
    if (nid < 0) return;
    float t = tanhf(score[i]);
    float v = X[(size_t)i * 128 + c] * t;
    Xn[(size_t)nid * 128 + c] = v;
    if (Xh) {
        f16 h = (f16)v;
        Xh[(size_t)nid * 128 + c] = h;
        Xl[(size_t)nid * 128 + c] = (f16)(v - (float)h);
    }
}

// ---------------- global max pool (parallel, encoded atomicMax) ----------------
__global__ void gmp2(const float* __restrict__ X, int npg, int rpb,
                     unsigned* __restrict__ outEnc)
{
    int b = blockIdx.x, q = blockIdx.y, c = threadIdx.x;  // 128 threads
    int r0 = q * rpb, r1 = min(npg, r0 + rpb);
    if (r0 >= r1) return;
    const float* p = X + ((size_t)b * npg + r0) * 128 + c;
    float m = -INFINITY;
    for (int i = r0; i < r1; ++i, p += 128) m = fmaxf(m, *p);
    atomicMax(&outEnc[b * 128 + c], enc_f(m));
}

// ---------------- final: relu((x1+x2+x3) @ Wf + bf), decoding gmp results ----------------
__global__ void final_mlp(const unsigned* __restrict__ xg,
                          const float* __restrict__ Wf,
                          const float* __restrict__ bf, float* __restrict__ out)
{
    int b = blockIdx.x, o = threadIdx.x;  // 64 threads
    float acc = bf[o];
    for (int c = 0; c < 128; ++c) {
        int i = b * 128 + c;
        float xv = dec_f(xg[i]) + dec_f(xg[4096 + i]) + dec_f(xg[8192 + i]);
        acc += xv * Wf[c * 64 + o];
    }
    out[b * 64 + o] = fmaxf(acc, 0.f);
}

// ---------------- host orchestration ----------------
static inline size_t alignup(size_t x) { return (x + 255) & ~(size_t)255; }

extern "C" void kernel_launch(void* const* d_in, const int* in_sizes, int n_in,
                              void* d_out, int out_size, void* d_ws, size_t ws_size,
                              hipStream_t stream)
{
    const float* x_feat = (const float*)d_in[0];
    const int*   ei     = (const int*)d_in[1];
    const float* Wl1  = (const float*)d_in[3];
    const float* bl1  = (const float*)d_in[4];
    const float* Wr1  = (const float*)d_in[5];
    const float* br1  = (const float*)d_in[6];
    const float* att1 = (const float*)d_in[7];
    const float* bias1= (const float*)d_in[8];
    const float* Wl2  = (const float*)d_in[9];
    const float* bl2  = (const float*)d_in[10];
    const float* Wr2  = (const float*)d_in[11];
    const float* br2  = (const float*)d_in[12];
    const float* att2 = (const float*)d_in[13];
    const float* bias2= (const float*)d_in[14];
    const float* Wsn  = (const float*)d_in[15];
    const float* Wsr  = (const float*)d_in[16];
    const float* bs   = (const float*)d_in[17];
    const float* Wf   = (const float*)d_in[18];
    const float* bf   = (const float*)d_in[19];
    float* out = (float*)d_out;

    const int* e_src = ei;
    const int* e_dst = ei + ETOT;

    // ---- workspace carve-up ----
    char* ws = (char*)d_ws;
    size_t o = 0;
    auto take = [&](size_t bytes) { size_t r = o; o = alignup(o + bytes); return r; };
    float* C1   = (float*)(ws + take((size_t)NTOT * 1024 * 4));  // XL|XR fp32 (both layers)
    float* H1   = (float*)(ws + take((size_t)NTOT * 128 * 4));
    float* PX   = (float*)(ws + take((size_t)N2 * 128 * 4));
    float* H2   = (float*)(ws + take((size_t)N2 * 128 * 4));
    float* P2X  = (float*)(ws + take((size_t)N3 * 128 * 4));
    f16*   Ah1  = (f16*)(ws + take((size_t)NTOT * 512 * 2));
    f16*   Al1  = (f16*)(ws + take((size_t)NTOT * 512 * 2));
    f16*   Wh1  = (f16*)(ws + take((size_t)1024 * 512 * 2));
    f16*   Wo1  = (f16*)(ws + take((size_t)1024 * 512 * 2));
    f16*   Wh2  = (f16*)(ws + take((size_t)1024 * 128 * 2));
    f16*   Wo2  = (f16*)(ws + take((size_t)1024 * 128 * 2));
    f16*   PXh  = (f16*)(ws + take((size_t)N2 * 128 * 2));
    f16*   PXl  = (f16*)(ws + take((size_t)N2 * 128 * 2));
    float* score= (float*)(ws + take((size_t)NTOT * 4));
    int*   nmap = (int*)(ws + take((size_t)NTOT * 4));
    int*   cnt  = (int*)(ws + take((size_t)(NTOT + 1) * 4));
    int*   offs = (int*)(ws + take((size_t)(NTOT + 1) * 4));
    int*   nxt  = (int*)(ws + take((size_t)(NTOT + 1) * 4));
    int*   csr1 = (int*)(ws + take((size_t)ETOT * 4));
    int*   es2  = (int*)(ws + take((size_t)ETOT * 4));
    int*   ed2  = (int*)(ws + take((size_t)ETOT * 4));
    int*   csr2 = (int*)(ws + take((size_t)ETOT * 4));
    int*   ec2  = (int*)(ws + take(256));
    unsigned* xg = (unsigned*)(ws + take((size_t)3 * NB * 128 * 4));  // x1|x2|x3 encoded
    (void)ws_size; (void)in_sizes; (void)n_in; (void)out_size;

    // ---- prep: split x_feat, transpose+split weights, zero readouts ----
    hipMemsetAsync(xg, 0, (size_t)3 * NB * 128 * 4, stream);
    split_a<<<(NTOT * 512 / 8) / 256, 256, 0, stream>>>(x_feat, Ah1, Al1, NTOT * 512 / 8);
    prep_w<<<dim3(512 / 32, 32), 256, 0, stream>>>(Wl1, Wr1, Wh1, Wo1, 512);
    prep_w<<<dim3(128 / 32, 32), 256, 0, stream>>>(Wl2, Wr2, Wh2, Wo2, 128);

    // ---- layer 1 transform: C1 = x @ [Wl1|Wr1] + [bl1|br1]  (split-fp16 MFMA) ----
    gemm_split<<<dim3(8, NTOT / 128), 256, 0, stream>>>(Ah1, Al1, Wh1, Wo1, bl1, br1, C1, NTOT, 512);

    // ---- CSR (by dst) ----
    hipMemsetAsync(cnt, 0, (size_t)(NTOT + 1) * 4, stream);
    count_edges<<<ETOT / 256, 256, 0, stream>>>(e_dst, ETOT, cnt);
    scan_excl<<<1, 1024, 0, stream>>>(cnt, NTOT, offs, nxt);
    fill_edges<<<ETOT / 256, 256, 0, stream>>>(e_src, e_dst, ETOT, nxt, csr1);

    // ---- GATv2 layer 1 + relu -> H1; x1 = gmp(H1) ----
    gatv2_agg<<<NTOT / 4, 256, 0, stream>>>(C1, C1 + 512, 1024, csr1, offs, att1, bias1, H1, NTOT);
    gmp2<<<dim3(NB, 8), 128, 0, stream>>>(H1, NPG, 64, xg);

    // ---- SAGE score 1 + pool 1 (emits fp16 split of PX); x2 = gmp(PX) ----
    sage_score<<<NTOT / 4, 256, 0, stream>>>(H1, csr1, offs, Wsn, Wsr, bs, score, NTOT);
    pool_rank<<<NB, 512, 0, stream>>>(score, NPG, K1, nmap);
    pool_gather<<<NTOT, 128, 0, stream>>>(H1, score, nmap, PX, PXh, PXl);
    gmp2<<<dim3(NB, 4), 128, 0, stream>>>(PX, K1, 77, xg + 4096);

    // ---- remap + compact edges, CSR2 ----
    hipMemsetAsync(cnt, 0, (size_t)(NTOT + 1) * 4, stream);
    hipMemsetAsync(ec2, 0, 4, stream);
    remap_edges<<<ETOT / 256, 256, 0, stream>>>(e_src, e_dst, ETOT, nmap, es2, ed2, ec2, cnt);
    scan_excl<<<1, 1024, 0, stream>>>(cnt, N2, offs, nxt);
    fill_edges_dyn<<<ETOT / 256, 256, 0, stream>>>(es2, ed2, ec2, nxt, csr2);

    // ---- layer 2 transform: C1 = PX @ [Wl2|Wr2] + [bl2|br2]  (K=128) ----
    gemm_split<<<dim3(8, N2 / 128), 256, 0, stream>>>(PXh, PXl, Wh2, Wo2, bl2, br2, C1, N2, 128);

    // ---- GATv2 layer 2 + relu -> H2 ----
    gatv2_agg<<<(N2 + 3) / 4, 256, 0, stream>>>(C1, C1 + 512, 1024, csr2, offs, att2, bias2, H2, N2);

    // ---- SAGE score 2 + pool 2; x3 = gmp(P2X) ----
    sage_score<<<(N2 + 3) / 4, 256, 0, stream>>>(H2, csr2, offs, Wsn, Wsr, bs, score, N2);
    pool_rank<<<NB, 512, 0, stream>>>(score, K1, K2, nmap);
    pool_gather<<<N2, 128, 0, stream>>>(H2, score, nmap, P2X, (f16*)nullptr, (f16*)nullptr);
    gmp2<<<dim3(NB, 4), 128, 0, stream>>>(P2X, K2, 47, xg + 8192);

    // ---- final MLP ----
    final_mlp<<<NB, 64, 0, stream>>>(xg, Wf, bf, out);
}

// Round 6
// 378.570 us; speedup vs baseline: 1.2447x; 1.2447x over previous
//
#include <hip/hip_runtime.h>
#include <hip/hip_bf16.h>
#include <math.h>

// ---------------- problem constants ----------------
#define NB    32          // graphs
#define NPG   512         // nodes per graph
#define NTOT  (NB*NPG)    // 16384
#define EPG   4096
#define ETOT  (NB*EPG)    // 131072
#define K1    308
#define K2    185
#define N2    (NB*K1)     // 9856  (=154*64, 77*128)
#define N3    (NB*K2)     // 5920
#define SLOPE 0.2f

typedef _Float16 f16;
typedef f16   f16x8 __attribute__((ext_vector_type(8)));
typedef float f32x4 __attribute__((ext_vector_type(4)));

// W pre-scale (power of 2, exact) keeps lo-split in fp16 normal range
#define WSCALE 512.0f
#define WINV   (1.0f/512.0f)

// monotone float <-> uint encoding (total order preserved)
__device__ __forceinline__ unsigned enc_f(float v) {
    unsigned u = __float_as_uint(v);
    return (u & 0x80000000u) ? ~u : (u | 0x80000000u);
}
__device__ __forceinline__ float dec_f(unsigned e) {
    return (e & 0x80000000u) ? __uint_as_float(e ^ 0x80000000u) : __uint_as_float(~e);
}

// async global->LDS, 16B per lane, wave-uniform LDS base, per-lane global src
__device__ __forceinline__ void gll16(const void* g, void* l)
{
    __builtin_amdgcn_global_load_lds(
        (const __attribute__((address_space(1))) unsigned int*)g,
        (__attribute__((address_space(3))) unsigned int*)l, 16, 0, 0);
}

// Packed operand layout (matches LDS tile exactly):
//   elem (r, k) -> P[(( (r>>6)*(K/8) + (k>>3) )*64 + (r&63))*8 + (k&7)]
// so a 64-row x 8-k chunk is 1 KB contiguous -> one fully-coalesced
// global_load_lds per (kblk, row-half) with linear LDS dest.

// ---------------- split fp32 -> (hi,lo) fp16, packed output ----------------
__global__ __launch_bounds__(256) void split_a(const float* __restrict__ A,
                                               f16* __restrict__ Ah, f16* __restrict__ Al,
                                               int K8, int nchunk)
{
    int j = blockIdx.x * 256 + threadIdx.x;   // chunk id in packed order
    if (j >= nchunk) return;
    int rr = j & 63;
    int tmp = j >> 6;            // tr*K8 + kb
    int kb = tmp % K8;
    int tr = tmp / K8;
    int r = tr * 64 + rr;
    const float* src = A + (size_t)r * (K8 * 8) + kb * 8;
    float4 v0 = *(const float4*)src;
    float4 v1 = *(const float4*)(src + 4);
    float v[8] = {v0.x, v0.y, v0.z, v0.w, v1.x, v1.y, v1.z, v1.w};
    f16x8 h, l;
#pragma unroll
    for (int q = 0; q < 8; ++q) {
        f16 hh = (f16)v[q];
        h[q] = hh;
        l[q] = (f16)(v[q] - (float)hh);
    }
    *(f16x8*)(Ah + (size_t)j * 8) = h;   // coalesced packed write
    *(f16x8*)(Al + (size_t)j * 8) = l;
}

// ---------------- W prep: concat L|R, transpose, scale, split, packed ----------------
__global__ __launch_bounds__(256) void prep_w(const float* __restrict__ WL,
                                              const float* __restrict__ WR,
                                              f16* __restrict__ Wh, f16* __restrict__ Wlo,
                                              int K)
{
    __shared__ float t[32][33];
    int bk = blockIdx.x;          // k tile (K/32)
    int bn = blockIdx.y;          // n tile (32 tiles of 32 over 1024)
    int tx = threadIdx.x & 31, ty = threadIdx.x >> 5;   // 32 x 8
    const float* Wsrc = (bn < 16) ? WL : WR;
    int ncol = bn * 32 - (bn < 16 ? 0 : 512) + tx;
    int K8 = K >> 3;
#pragma unroll
    for (int q = 0; q < 4; ++q) {
        int kk = bk * 32 + ty + q * 8;
        t[ty + q * 8][tx] = Wsrc[(size_t)kk * 512 + ncol];
    }
    __syncthreads();
#pragma unroll
    for (int q = 0; q < 4; ++q) {
        int n = bn * 32 + ty + q * 8;
        int k = bk * 32 + tx;
        float v = t[tx][ty + q * 8] * WSCALE;
        f16 h = (f16)v;
        size_t off = (((size_t)(n >> 6) * K8 + (k >> 3)) * 64 + (n & 63)) * 8 + (k & 7);
        Wh [off] = h;
        Wlo[off] = (f16)(v - (float)h);
    }
}

// ---------------- split-fp16 MFMA GEMM: packed operands, counted vmcnt ----------------
// C[M,1024] = (Ah+Al)[M,K] @ (Wh+Wlo)^T[K,1024] * WINV + bias(l|r)
// block: 256 thr / 4 waves; tile 128x128; BK=32; wave w owns 64x64 quadrant;
// wave w stages matrix w (Ah/Al/Bh/Bl). 2 LDS buffers (64KB, 2 blocks/CU).
__global__ __launch_bounds__(256) void gemm_split(
    const f16* __restrict__ Ah, const f16* __restrict__ Al,
    const f16* __restrict__ Bh, const f16* __restrict__ Bl,
    const float* __restrict__ bias_l, const float* __restrict__ bias_r,
    float* __restrict__ C, int M, int K)
{
    __shared__ f16 sm[2][4][4][128][8];   // [buf][mat][kblk][row][8k] = 64 KB
    const int Nn = 1024;
    int tid = threadIdx.x;
    int wave = tid >> 6, lane = tid & 63;

    // col-major tile assignment: blocks with consecutive linear ids share a B col-panel
    // (round-robin XCD dispatch then keeps that panel hot in each XCD's L2)
    int l = blockIdx.y * gridDim.x + blockIdx.x;
    int rows = gridDim.y;
    int row0 = (l % rows) * 128, col0 = (l / rows) * 128;

    const f16* base = (wave == 0) ? Ah : (wave == 1) ? Al : (wave == 2) ? Bh : Bl;
    int rc0 = (wave < 2) ? row0 : col0;
    int tr0 = rc0 >> 6;

    int wr = wave >> 1, wc = wave & 1;
    int r16 = lane & 15, kb = lane >> 4;

    const int K8 = K >> 3;
    const int nt = K >> 5;   // K/32 tiles

    // stage K-tile t into buffer buf: 8 x (1KB contiguous global -> linear LDS)
    auto stage = [&](int buf, int t) {
#pragma unroll
        for (int i = 0; i < 8; ++i) {
            int kblk = i >> 1, rh = i & 1;
            const f16* src = base + ((((size_t)(tr0 + rh)) * K8 + (t * 4 + kblk)) << 9) + lane * 8;
            gll16(src, &sm[buf][wave][kblk][rh * 64][0]);
        }
    };

    f32x4 acc[4][4] = {};
    int cur = 0;
    stage(0, 0);

    for (int t = 0; t < nt; ++t) {
        if (t + 1 < nt) {
            stage(cur ^ 1, t + 1);                         // prefetch next tile
            asm volatile("s_waitcnt vmcnt(8)" ::: "memory"); // wait tile t only (newest 8 = t+1)
        } else {
            asm volatile("s_waitcnt vmcnt(0)" ::: "memory");
        }
        __builtin_amdgcn_s_barrier();   // all waves' tile-t shares visible

        f16x8 a_h[4], a_l[4], b_h[4], b_l[4];
#pragma unroll
        for (int m = 0; m < 4; ++m) {
            a_h[m] = *(const f16x8*)&sm[cur][0][kb][wr * 64 + m * 16 + r16][0];
            a_l[m] = *(const f16x8*)&sm[cur][1][kb][wr * 64 + m * 16 + r16][0];
        }
#pragma unroll
        for (int n = 0; n < 4; ++n) {
            b_h[n] = *(const f16x8*)&sm[cur][2][kb][wc * 64 + n * 16 + r16][0];
            b_l[n] = *(const f16x8*)&sm[cur][3][kb][wc * 64 + n * 16 + r16][0];
        }
        // term-major: 16 independent MFMAs between accumulator reuses;
        // per-acc order stays hh -> hl -> lh (fixed accumulation order)
#pragma unroll
        for (int m = 0; m < 4; ++m)
#pragma unroll
            for (int n = 0; n < 4; ++n)
                acc[m][n] = __builtin_amdgcn_mfma_f32_16x16x32_f16(a_h[m], b_h[n], acc[m][n], 0, 0, 0);
#pragma unroll
        for (int m = 0; m < 4; ++m)
#pragma unroll
            for (int n = 0; n < 4; ++n)
                acc[m][n] = __builtin_amdgcn_mfma_f32_16x16x32_f16(a_h[m], b_l[n], acc[m][n], 0, 0, 0);
#pragma unroll
        for (int m = 0; m < 4; ++m)
#pragma unroll
            for (int n = 0; n < 4; ++n)
                acc[m][n] = __builtin_amdgcn_mfma_f32_16x16x32_f16(a_l[m], b_h[n], acc[m][n], 0, 0, 0);

        __syncthreads();   // all reads of buf `cur` done before it is re-staged next iter
        cur ^= 1;
    }
    // epilogue: C/D frag: col = lane&15, row = (lane>>4)*4 + j
#pragma unroll
    for (int m = 0; m < 4; ++m)
#pragma unroll
        for (int n = 0; n < 4; ++n) {
            int cc = col0 + wc * 64 + n * 16 + r16;
            float b = (cc < 512) ? bias_l[cc] : bias_r[cc - 512];
#pragma unroll
            for (int j = 0; j < 4; ++j) {
                int rr = row0 + wr * 64 + m * 16 + kb * 4 + j;
                C[(size_t)rr * Nn + cc] = acc[m][n][j] * WINV + b;
            }
        }
}

// ---------------- CSR build ----------------
__global__ void count_edges(const int* __restrict__ dst, int E_in, int* __restrict__ cnt)
{
    int e = blockIdx.x * blockDim.x + threadIdx.x;
    if (e < E_in) atomicAdd(&cnt[dst[e]], 1);
}

__global__ void fill_edges(const int* __restrict__ src, const int* __restrict__ dst,
                           int E_in, int* __restrict__ next, int* __restrict__ csr)
{
    int e = blockIdx.x * blockDim.x + threadIdx.x;
    if (e < E_in) {
        int p = atomicAdd(&next[dst[e]], 1);
        csr[p] = src[e];
    }
}

__global__ __launch_bounds__(1024) void scan_excl(const int* __restrict__ cnt, int n,
                                                  int* __restrict__ off, int* __restrict__ next)
{
    __shared__ int bsum[1024];
    int t = threadIdx.x;
    int chunk = (n + 1023) >> 10;
    int lo = t * chunk, hi = min(n, lo + chunk);
    int s = 0;
    for (int i = lo; i < hi; ++i) s += cnt[i];
    bsum[t] = s;
    __syncthreads();
    for (int d = 1; d < 1024; d <<= 1) {
        int v = (t >= d) ? bsum[t - d] : 0;
        __syncthreads();
        bsum[t] += v;
        __syncthreads();
    }
    int run = t ? bsum[t - 1] : 0;
    for (int i = lo; i < hi; ++i) { off[i] = run; next[i] = run; run += cnt[i]; }
    if (t == 1023) off[n] = bsum[1023];
}

__global__ void remap_edges(const int* __restrict__ src, const int* __restrict__ dst,
                            int E_in, const int* __restrict__ nmap,
                            int* __restrict__ es2, int* __restrict__ ed2,
                            int* __restrict__ ec2, int* __restrict__ cnt2)
{
    int e = blockIdx.x * blockDim.x + threadIdx.x;
    if (e >= E_in) return;
    int ns = nmap[src[e]], nd = nmap[dst[e]];
    if (ns >= 0 && nd >= 0) {
        int pos = atomicAdd(ec2, 1);
        es2[pos] = ns; ed2[pos] = nd;
        atomicAdd(&cnt2[nd], 1);
    }
}

__global__ void fill_edges_dyn(const int* __restrict__ es, const int* __restrict__ ed,
                               const int* __restrict__ ec, int* __restrict__ next,
                               int* __restrict__ csr)
{
    int e = blockIdx.x * blockDim.x + threadIdx.x;
    if (e < *ec) {
        int p = atomicAdd(&next[ed[e]], 1);
        csr[p] = es[e];
    }
}

// ---------------- GATv2 aggregation: one wave per dst node ----------------
__global__ __launch_bounds__(256) void gatv2_agg(
    const float* __restrict__ XL, const float* __restrict__ XR, int ldx,
    const int* __restrict__ csr_src, const int* __restrict__ off,
    const float* __restrict__ att, const float* __restrict__ bias,
    float* __restrict__ out, int n)
{
    int nwg = gridDim.x;
    int q = nwg >> 3;
    int swz = (blockIdx.x & 7) * q + (blockIdx.x >> 3);
    int wid = swz * 4 + (threadIdx.x >> 6);
    int lane = threadIdx.x & 63;
    if (wid >= n) return;
    const int f0 = lane * 8;
    float xr[8], atv[8], acc[8];
    {
        float4 r0 = *(const float4*)&XR[(size_t)wid * ldx + f0];
        float4 r1 = *(const float4*)&XR[(size_t)wid * ldx + f0 + 4];
        xr[0]=r0.x; xr[1]=r0.y; xr[2]=r0.z; xr[3]=r0.w;
        xr[4]=r1.x; xr[5]=r1.y; xr[6]=r1.z; xr[7]=r1.w;
        float4 t0 = *(const float4*)&att[f0];
        float4 t1 = *(const float4*)&att[f0 + 4];
        atv[0]=t0.x; atv[1]=t0.y; atv[2]=t0.z; atv[3]=t0.w;
        atv[4]=t1.x; atv[5]=t1.y; atv[6]=t1.z; atv[7]=t1.w;
#pragma unroll
        for (int j = 0; j < 8; ++j) acc[j] = 0.f;
    }
    float m = -INFINITY, ssum = 0.f;
    int e0 = off[wid], e1 = off[wid + 1];
    for (int e = e0 - 1; e < e1; ++e) {
        int s = (e < e0) ? wid : csr_src[e];
        float xl[8], part = 0.f;
        float4 l0 = *(const float4*)&XL[(size_t)s * ldx + f0];
        float4 l1 = *(const float4*)&XL[(size_t)s * ldx + f0 + 4];
        xl[0]=l0.x; xl[1]=l0.y; xl[2]=l0.z; xl[3]=l0.w;
        xl[4]=l1.x; xl[5]=l1.y; xl[6]=l1.z; xl[7]=l1.w;
#pragma unroll
        for (int j = 0; j < 8; ++j) {
            float v = xl[j] + xr[j];
            v = (v > 0.f) ? v : SLOPE * v;
            part += v * atv[j];
        }
        part += __shfl_xor(part, 1);
        part += __shfl_xor(part, 2);
        part += __shfl_xor(part, 4);
        part += __shfl_xor(part, 8);
        float mn = fmaxf(m, part);
        float scale = __expf(m - mn);
        float p = __expf(part - mn);
        ssum = ssum * scale + p;
#pragma unroll
        for (int j = 0; j < 8; ++j) acc[j] = acc[j] * scale + p * xl[j];
        m = mn;
    }
    float inv = 1.f / ssum;
#pragma unroll
    for (int j = 0; j < 8; ++j) {
        float v = acc[j] * inv;
        v += __shfl_xor(v, 16);
        v += __shfl_xor(v, 32);
        if (lane < 16) {
            int c = lane * 8 + j;
            float r = 0.25f * v + bias[c];
            out[(size_t)wid * 128 + c] = fmaxf(r, 0.f);
        }
    }
}

// ---------------- SAGE pooling score ----------------
__global__ __launch_bounds__(256) void sage_score(
    const float* __restrict__ X, const int* __restrict__ csr_src,
    const int* __restrict__ off, const float* __restrict__ Wn,
    const float* __restrict__ Wr, const float* __restrict__ bs,
    float* __restrict__ score, int n)
{
    int wid = (blockIdx.x * blockDim.x + threadIdx.x) >> 6;
    int lane = threadIdx.x & 63;
    if (wid >= n) return;
    int c0 = lane * 2;
    int e0 = off[wid], e1 = off[wid + 1];
    float a0 = 0.f, a1 = 0.f;
    for (int e = e0; e < e1; ++e) {
        int s = csr_src[e];
        float2 v = *(const float2*)&X[(size_t)s * 128 + c0];
        a0 += v.x; a1 += v.y;
    }
    float inv = 1.f / fmaxf((float)(e1 - e0), 1.f);
    float2 xv = *(const float2*)&X[(size_t)wid * 128 + c0];
    float part = a0 * inv * Wn[c0] + a1 * inv * Wn[c0 + 1] + xv.x * Wr[c0] + xv.y * Wr[c0 + 1];
#pragma unroll
    for (int sh = 1; sh < 64; sh <<= 1) part += __shfl_xor(part, sh);
    if (lane == 0) score[wid] = part + bs[0];
}

// ---------------- SAGPooling top-k (exact jax.lax.top_k rank) ----------------
__global__ __launch_bounds__(512) void pool_rank(const float* __restrict__ score,
                                                 int npg, int k, int* __restrict__ nmap)
{
    __shared__ float s[512];
    int b = blockIdx.x, t = threadIdx.x;
    const float* sc = score + (size_t)b * npg;
    if (t < npg) s[t] = sc[t];
    __syncthreads();
    if (t < npg) {
        float mine = s[t];
        int rank = 0;
        for (int j = 0; j < npg; ++j) {
            float v = s[j];
            rank += (v > mine) || (v == mine && j < t);
        }
        nmap[(size_t)b * npg + t] = (rank < k) ? (b * k + rank) : -1;
    }
}

// gather + tanh gate; optionally emit packed fp16 split for the next GEMM (K=128)
__global__ void pool_gather(const float* __restrict__ X, const float* __restrict__ score,
                            const int* __restrict__ nmap, float* __restrict__ Xn,
                            f16* __restrict__ Xh, f16* __restrict__ Xl)
{
    int i = blockIdx.x, c = threadIdx.x;  // 128 threads
    int nid = nmap[i];
    if (nid < 0) return;
    float t = tanhf(score[i]);
    float v = X[(size_t)i * 128 + c] * t;
    Xn[(size_t)nid * 128 + c] = v;
    if (Xh) {
        f16 h = (f16)v;
        size_t off = (((size_t)(nid >> 6) * 16 + (c >> 3)) * 64 + (nid & 63)) * 8 + (c & 7);
        Xh[off] = h;
        Xl[off] = (f16)(v - (float)h);
    }
}

// ---------------- global max pool (parallel, encoded atomicMax) ----------------
__global__ void gmp2(const float* __restrict__ X, int npg, int rpb,
                     unsigned* __restrict__ outEnc)
{
    int b = blockIdx.x, q = blockIdx.y, c = threadIdx.x;  // 128 threads
    int r0 = q * rpb, r1 = min(npg, r0 + rpb);
    if (r0 >= r1) return;
    const float* p = X + ((size_t)b * npg + r0) * 128 + c;
    float m = -INFINITY;
    for (int i = r0; i < r1; ++i, p += 128) m = fmaxf(m, *p);
    atomicMax(&outEnc[b * 128 + c], enc_f(m));
}

// ---------------- final: relu((x1+x2+x3) @ Wf + bf), decoding gmp results ----------------
__global__ void final_mlp(const unsigned* __restrict__ xg,
                          const float* __restrict__ Wf,
                          const float* __restrict__ bf, float* __restrict__ out)
{
    int b = blockIdx.x, o = threadIdx.x;  // 64 threads
    float acc = bf[o];
    for (int c = 0; c < 128; ++c) {
        int i = b * 128 + c;
        float xv = dec_f(xg[i]) + dec_f(xg[4096 + i]) + dec_f(xg[8192 + i]);
        acc += xv * Wf[c * 64 + o];
    }
    out[b * 64 + o] = fmaxf(acc, 0.f);
}

// ---------------- host orchestration ----------------
static inline size_t alignup(size_t x) { return (x + 255) & ~(size_t)255; }

extern "C" void kernel_launch(void* const* d_in, const int* in_sizes, int n_in,
                              void* d_out, int out_size, void* d_ws, size_t ws_size,
                              hipStream_t stream)
{
    const float* x_feat = (const float*)d_in[0];
    const int*   ei     = (const int*)d_in[1];
    const float* Wl1  = (const float*)d_in[3];
    const float* bl1  = (const float*)d_in[4];
    const float* Wr1  = (const float*)d_in[5];
    const float* br1  = (const float*)d_in[6];
    const float* att1 = (const float*)d_in[7];
    const float* bias1= (const float*)d_in[8];
    const float* Wl2  = (const float*)d_in[9];
    const float* bl2  = (const float*)d_in[10];
    const float* Wr2  = (const float*)d_in[11];
    const float* br2  = (const float*)d_in[12];
    const float* att2 = (const float*)d_in[13];
    const float* bias2= (const float*)d_in[14];
    const float* Wsn  = (const float*)d_in[15];
    const float* Wsr  = (const float*)d_in[16];
    const float* bs   = (const float*)d_in[17];
    const float* Wf   = (const float*)d_in[18];
    const float* bf   = (const float*)d_in[19];
    float* out = (float*)d_out;

    const int* e_src = ei;
    const int* e_dst = ei + ETOT;

    // ---- workspace carve-up ----
    char* ws = (char*)d_ws;
    size_t o = 0;
    auto take = [&](size_t bytes) { size_t r = o; o = alignup(o + bytes); return r; };
    float* C1   = (float*)(ws + take((size_t)NTOT * 1024 * 4));  // XL|XR fp32 (both layers)
    float* H1   = (float*)(ws + take((size_t)NTOT * 128 * 4));
    float* PX   = (float*)(ws + take((size_t)N2 * 128 * 4));
    float* H2   = (float*)(ws + take((size_t)N2 * 128 * 4));
    float* P2X  = (float*)(ws + take((size_t)N3 * 128 * 4));
    f16*   Ah1  = (f16*)(ws + take((size_t)NTOT * 512 * 2));
    f16*   Al1  = (f16*)(ws + take((size_t)NTOT * 512 * 2));
    f16*   Wh1  = (f16*)(ws + take((size_t)1024 * 512 * 2));
    f16*   Wo1  = (f16*)(ws + take((size_t)1024 * 512 * 2));
    f16*   Wh2  = (f16*)(ws + take((size_t)1024 * 128 * 2));
    f16*   Wo2  = (f16*)(ws + take((size_t)1024 * 128 * 2));
    f16*   PXh  = (f16*)(ws + take((size_t)N2 * 128 * 2));
    f16*   PXl  = (f16*)(ws + take((size_t)N2 * 128 * 2));
    float* score= (float*)(ws + take((size_t)NTOT * 4));
    int*   nmap = (int*)(ws + take((size_t)NTOT * 4));
    int*   cnt  = (int*)(ws + take((size_t)(NTOT + 1) * 4));
    int*   offs = (int*)(ws + take((size_t)(NTOT + 1) * 4));
    int*   nxt  = (int*)(ws + take((size_t)(NTOT + 1) * 4));
    int*   csr1 = (int*)(ws + take((size_t)ETOT * 4));
    int*   es2  = (int*)(ws + take((size_t)ETOT * 4));
    int*   ed2  = (int*)(ws + take((size_t)ETOT * 4));
    int*   csr2 = (int*)(ws + take((size_t)ETOT * 4));
    int*   ec2  = (int*)(ws + take(256));
    unsigned* xg = (unsigned*)(ws + take((size_t)3 * NB * 128 * 4));  // x1|x2|x3 encoded
    (void)ws_size; (void)in_sizes; (void)n_in; (void)out_size;

    // ---- prep: split x_feat (packed), transpose+split weights (packed), zero readouts ----
    hipMemsetAsync(xg, 0, (size_t)3 * NB * 128 * 4, stream);
    split_a<<<(NTOT * 512 / 8 + 255) / 256, 256, 0, stream>>>(x_feat, Ah1, Al1, 64, NTOT * 512 / 8);
    prep_w<<<dim3(512 / 32, 32), 256, 0, stream>>>(Wl1, Wr1, Wh1, Wo1, 512);
    prep_w<<<dim3(128 / 32, 32), 256, 0, stream>>>(Wl2, Wr2, Wh2, Wo2, 128);

    // ---- layer 1 transform: C1 = x @ [Wl1|Wr1] + [bl1|br1]  (split-fp16 MFMA) ----
    gemm_split<<<dim3(8, NTOT / 128), 256, 0, stream>>>(Ah1, Al1, Wh1, Wo1, bl1, br1, C1, NTOT, 512);

    // ---- CSR (by dst) ----
    hipMemsetAsync(cnt, 0, (size_t)(NTOT + 1) * 4, stream);
    count_edges<<<ETOT / 256, 256, 0, stream>>>(e_dst, ETOT, cnt);
    scan_excl<<<1, 1024, 0, stream>>>(cnt, NTOT, offs, nxt);
    fill_edges<<<ETOT / 256, 256, 0, stream>>>(e_src, e_dst, ETOT, nxt, csr1);

    // ---- GATv2 layer 1 + relu -> H1; x1 = gmp(H1) ----
    gatv2_agg<<<NTOT / 4, 256, 0, stream>>>(C1, C1 + 512, 1024, csr1, offs, att1, bias1, H1, NTOT);
    gmp2<<<dim3(NB, 8), 128, 0, stream>>>(H1, NPG, 64, xg);

    // ---- SAGE score 1 + pool 1 (emits packed fp16 split of PX); x2 = gmp(PX) ----
    sage_score<<<NTOT / 4, 256, 0, stream>>>(H1, csr1, offs, Wsn, Wsr, bs, score, NTOT);
    pool_rank<<<NB, 512, 0, stream>>>(score, NPG, K1, nmap);
    pool_gather<<<NTOT, 128, 0, stream>>>(H1, score, nmap, PX, PXh, PXl);
    gmp2<<<dim3(NB, 4), 128, 0, stream>>>(PX, K1, 77, xg + 4096);

    // ---- remap + compact edges, CSR2 ----
    hipMemsetAsync(cnt, 0, (size_t)(NTOT + 1) * 4, stream);
    hipMemsetAsync(ec2, 0, 4, stream);
    remap_edges<<<ETOT / 256, 256, 0, stream>>>(e_src, e_dst, ETOT, nmap, es2, ed2, ec2, cnt);
    scan_excl<<<1, 1024, 0, stream>>>(cnt, N2, offs, nxt);
    fill_edges_dyn<<<ETOT / 256, 256, 0, stream>>>(es2, ed2, ec2, nxt, csr2);

    // ---- layer 2 transform: C1 = PX @ [Wl2|Wr2] + [bl2|br2]  (K=128) ----
    gemm_split<<<dim3(8, N2 / 128), 256, 0, stream>>>(PXh, PXl, Wh2, Wo2, bl2, br2, C1, N2, 128);

    // ---- GATv2 layer 2 + relu -> H2 ----
    gatv2_agg<<<(N2 + 3) / 4, 256, 0, stream>>>(C1, C1 + 512, 1024, csr2, offs, att2, bias2, H2, N2);

    // ---- SAGE score 2 + pool 2; x3 = gmp(P2X) ----
    sage_score<<<(N2 + 3) / 4, 256, 0, stream>>>(H2, csr2, offs, Wsn, Wsr, bs, score, N2);
    pool_rank<<<NB, 512, 0, stream>>>(score, K1, K2, nmap);
    pool_gather<<<N2, 128, 0, stream>>>(H2, score, nmap, P2X, (f16*)nullptr, (f16*)nullptr);
    gmp2<<<dim3(NB, 4), 128, 0, stream>>>(P2X, K2, 47, xg + 8192);

    // ---- final MLP ----
    final_mlp<<<NB, 64, 0, stream>>>(xg, Wf, bf, out);
}

// Round 7
// 333.955 us; speedup vs baseline: 1.4110x; 1.1336x over previous
//
#include <hip/hip_runtime.h>
#include <hip/hip_bf16.h>
#include <math.h>

// ---------------- problem constants ----------------
#define NB    32          // graphs
#define NPG   512         // nodes per graph
#define NTOT  (NB*NPG)    // 16384
#define EPG   4096
#define ETOT  (NB*EPG)    // 131072
#define K1    308
#define K2    185
#define N2    (NB*K1)     // 9856
#define N3    (NB*K2)     // 5920
#define SLOPE 0.2f

typedef _Float16 f16;
typedef f16   f16x8 __attribute__((ext_vector_type(8)));
typedef float f32x4 __attribute__((ext_vector_type(4)));

// W pre-scale (power of 2, exact) keeps lo-split in fp16 normal range
#define WSCALE 512.0f
#define WINV   (1.0f/512.0f)

// monotone float <-> uint encoding (total order preserved)
__device__ __forceinline__ unsigned enc_f(float v) {
    unsigned u = __float_as_uint(v);
    return (u & 0x80000000u) ? ~u : (u | 0x80000000u);
}
__device__ __forceinline__ float dec_f(unsigned e) {
    return (e & 0x80000000u) ? __uint_as_float(e ^ 0x80000000u) : __uint_as_float(~e);
}

// async global->LDS, 16B per lane, wave-uniform LDS base, per-lane global src
__device__ __forceinline__ void gll16(const void* g, void* l)
{
    __builtin_amdgcn_global_load_lds(
        (const __attribute__((address_space(1))) unsigned int*)g,
        (__attribute__((address_space(3))) unsigned int*)l, 16, 0, 0);
}

// Packed operand layout (matches GEMM LDS tile exactly):
//   elem (r, k) -> P[(( (r>>6)*(K/8) + (k>>3) )*64 + (r&63))*8 + (k&7)]
// -> each 64-row x 8-k chunk is 1 KB contiguous.

// ---------------- split fp32 -> (hi,lo) fp16, packed, LDS-transposed ----------------
// grid: (K/64, M/64), 256 thr. Also zeroes xg + cnt (runs first in the stream).
__global__ __launch_bounds__(256) void split_a(const float* __restrict__ A,
                                               f16* __restrict__ Ah, f16* __restrict__ Al,
                                               int K8, unsigned* __restrict__ xg,
                                               int* __restrict__ cnt)
{
    __shared__ float tile[64][65];
    int t = threadIdx.x;
    int kx = blockIdx.x, ry = blockIdx.y;
    int gid = (ry * gridDim.x + kx) * 256 + t;
    if (gid < 1536) xg[gid] = 0u;                       // zero readout buffer
    if (gid >= 2048 && gid < 2048 + NTOT + 8) cnt[gid - 2048] = 0;  // zero CSR1 counts

    int K = K8 * 8;
    // read 64x64 fp32 tile, coalesced (256B contiguous per 4-lane row group)
    int r = t >> 2, q = t & 3;
    const float* src = A + (size_t)(ry * 64 + r) * K + kx * 64 + q * 16;
#pragma unroll
    for (int i = 0; i < 4; ++i) {
        float4 v = *(const float4*)(src + i * 4);
        tile[r][q * 16 + i * 4 + 0] = v.x;
        tile[r][q * 16 + i * 4 + 1] = v.y;
        tile[r][q * 16 + i * 4 + 2] = v.z;
        tile[r][q * 16 + i * 4 + 3] = v.w;
    }
    __syncthreads();
    // write packed: thread t -> (rr = t&63, kb = t>>6 and +4); 1KB contiguous per wave
    int rr = t & 63, kb0 = t >> 6;
#pragma unroll
    for (int kk = 0; kk < 2; ++kk) {
        int kb = kb0 + kk * 4;
        f16x8 h, l;
#pragma unroll
        for (int c = 0; c < 8; ++c) {
            float v = tile[rr][kb * 8 + c];
            f16 hh = (f16)v;
            h[c] = hh;
            l[c] = (f16)(v - (float)hh);
        }
        size_t off = (((size_t)ry * K8 + kx * 8 + kb) * 64 + rr) * 8;
        *(f16x8*)(Ah + off) = h;
        *(f16x8*)(Al + off) = l;
    }
}

// ---------------- W prep: concat L|R, transpose, scale, split, packed ----------------
__global__ __launch_bounds__(256) void prep_w(const float* __restrict__ WL,
                                              const float* __restrict__ WR,
                                              f16* __restrict__ Wh, f16* __restrict__ Wlo,
                                              int K)
{
    __shared__ float t[32][33];
    int bk = blockIdx.x;          // k tile (K/32)
    int bn = blockIdx.y;          // n tile (32 tiles of 32 over 1024)
    int tx = threadIdx.x & 31, ty = threadIdx.x >> 5;   // 32 x 8
    const float* Wsrc = (bn < 16) ? WL : WR;
    int ncol = bn * 32 - (bn < 16 ? 0 : 512) + tx;
    int K8 = K >> 3;
#pragma unroll
    for (int q = 0; q < 4; ++q) {
        int kk = bk * 32 + ty + q * 8;
        t[ty + q * 8][tx] = Wsrc[(size_t)kk * 512 + ncol];
    }
    __syncthreads();
#pragma unroll
    for (int q = 0; q < 4; ++q) {
        int n = bn * 32 + ty + q * 8;
        int k = bk * 32 + tx;
        float v = t[tx][ty + q * 8] * WSCALE;
        f16 h = (f16)v;
        size_t off = (((size_t)(n >> 6) * K8 + (k >> 3)) * 64 + (n & 63)) * 8 + (k & 7);
        Wh [off] = h;
        Wlo[off] = (f16)(v - (float)h);
    }
}

// ---------------- split-fp16 MFMA GEMM: packed operands, counted vmcnt ----------------
__global__ __launch_bounds__(256) void gemm_split(
    const f16* __restrict__ Ah, const f16* __restrict__ Al,
    const f16* __restrict__ Bh, const f16* __restrict__ Bl,
    const float* __restrict__ bias_l, const float* __restrict__ bias_r,
    float* __restrict__ C, int M, int K)
{
    __shared__ f16 sm[2][4][4][128][8];   // [buf][mat][kblk][row][8k] = 64 KB
    const int Nn = 1024;
    int tid = threadIdx.x;
    int wave = tid >> 6, lane = tid & 63;

    // col-major tile assignment (panel sharing within each XCD's L2)
    int l = blockIdx.y * gridDim.x + blockIdx.x;
    int rows = gridDim.y;
    int row0 = (l % rows) * 128, col0 = (l / rows) * 128;

    const f16* base = (wave == 0) ? Ah : (wave == 1) ? Al : (wave == 2) ? Bh : Bl;
    int rc0 = (wave < 2) ? row0 : col0;
    int tr0 = rc0 >> 6;

    int wr = wave >> 1, wc = wave & 1;
    int r16 = lane & 15, kb = lane >> 4;

    const int K8 = K >> 3;
    const int nt = K >> 5;   // K/32 tiles

    auto stage = [&](int buf, int t) {
#pragma unroll
        for (int i = 0; i < 8; ++i) {
            int kblk = i >> 1, rh = i & 1;
            const f16* src = base + ((((size_t)(tr0 + rh)) * K8 + (t * 4 + kblk)) << 9) + lane * 8;
            gll16(src, &sm[buf][wave][kblk][rh * 64][0]);
        }
    };

    f32x4 acc[4][4] = {};
    int cur = 0;
    stage(0, 0);

    for (int t = 0; t < nt; ++t) {
        if (t + 1 < nt) {
            stage(cur ^ 1, t + 1);
            asm volatile("s_waitcnt vmcnt(8)" ::: "memory");
        } else {
            asm volatile("s_waitcnt vmcnt(0)" ::: "memory");
        }
        __builtin_amdgcn_s_barrier();

        f16x8 a_h[4], a_l[4], b_h[4], b_l[4];
#pragma unroll
        for (int m = 0; m < 4; ++m) {
            a_h[m] = *(const f16x8*)&sm[cur][0][kb][wr * 64 + m * 16 + r16][0];
            a_l[m] = *(const f16x8*)&sm[cur][1][kb][wr * 64 + m * 16 + r16][0];
        }
#pragma unroll
        for (int n = 0; n < 4; ++n) {
            b_h[n] = *(const f16x8*)&sm[cur][2][kb][wc * 64 + n * 16 + r16][0];
            b_l[n] = *(const f16x8*)&sm[cur][3][kb][wc * 64 + n * 16 + r16][0];
        }
#pragma unroll
        for (int m = 0; m < 4; ++m)
#pragma unroll
            for (int n = 0; n < 4; ++n)
                acc[m][n] = __builtin_amdgcn_mfma_f32_16x16x32_f16(a_h[m], b_h[n], acc[m][n], 0, 0, 0);
#pragma unroll
        for (int m = 0; m < 4; ++m)
#pragma unroll
            for (int n = 0; n < 4; ++n)
                acc[m][n] = __builtin_amdgcn_mfma_f32_16x16x32_f16(a_h[m], b_l[n], acc[m][n], 0, 0, 0);
#pragma unroll
        for (int m = 0; m < 4; ++m)
#pragma unroll
            for (int n = 0; n < 4; ++n)
                acc[m][n] = __builtin_amdgcn_mfma_f32_16x16x32_f16(a_l[m], b_h[n], acc[m][n], 0, 0, 0);

        __syncthreads();
        cur ^= 1;
    }
#pragma unroll
    for (int m = 0; m < 4; ++m)
#pragma unroll
        for (int n = 0; n < 4; ++n) {
            int cc = col0 + wc * 64 + n * 16 + r16;
            float b = (cc < 512) ? bias_l[cc] : bias_r[cc - 512];
#pragma unroll
            for (int j = 0; j < 4; ++j) {
                int rr = row0 + wr * 64 + m * 16 + kb * 4 + j;
                C[(size_t)rr * Nn + cc] = acc[m][n][j] * WINV + b;
            }
        }
}

// ---------------- CSR build ----------------
__global__ void count_edges(const int* __restrict__ dst, int E_in, int* __restrict__ cnt)
{
    int e = blockIdx.x * blockDim.x + threadIdx.x;
    if (e < E_in) atomicAdd(&cnt[dst[e]], 1);
}

__global__ void fill_edges(const int* __restrict__ src, const int* __restrict__ dst,
                           int E_in, int* __restrict__ next, int* __restrict__ csr)
{
    int e = blockIdx.x * blockDim.x + threadIdx.x;
    if (e < E_in) {
        int p = atomicAdd(&next[dst[e]], 1);
        csr[p] = src[e];
    }
}

__global__ __launch_bounds__(1024) void scan_excl(const int* __restrict__ cnt, int n,
                                                  int* __restrict__ off, int* __restrict__ next)
{
    __shared__ int bsum[1024];
    int t = threadIdx.x;
    int chunk = (n + 1023) >> 10;
    int lo = t * chunk, hi = min(n, lo + chunk);
    int s = 0;
    for (int i = lo; i < hi; ++i) s += cnt[i];
    bsum[t] = s;
    __syncthreads();
    for (int d = 1; d < 1024; d <<= 1) {
        int v = (t >= d) ? bsum[t - d] : 0;
        __syncthreads();
        bsum[t] += v;
        __syncthreads();
    }
    int run = t ? bsum[t - 1] : 0;
    for (int i = lo; i < hi; ++i) { off[i] = run; next[i] = run; run += cnt[i]; }
    if (t == 1023) off[n] = bsum[1023];
}

__global__ void remap_edges(const int* __restrict__ src, const int* __restrict__ dst,
                            int E_in, const int* __restrict__ nmap,
                            int* __restrict__ es2, int* __restrict__ ed2,
                            int* __restrict__ ec2, int* __restrict__ cnt2)
{
    int e = blockIdx.x * blockDim.x + threadIdx.x;
    if (e >= E_in) return;
    int ns = nmap[src[e]], nd = nmap[dst[e]];
    if (ns >= 0 && nd >= 0) {
        int pos = atomicAdd(ec2, 1);
        es2[pos] = ns; ed2[pos] = nd;
        atomicAdd(&cnt2[nd], 1);
    }
}

__global__ void fill_edges_dyn(const int* __restrict__ es, const int* __restrict__ ed,
                               const int* __restrict__ ec, int* __restrict__ next,
                               int* __restrict__ csr)
{
    int e = blockIdx.x * blockDim.x + threadIdx.x;
    if (e < *ec) {
        int p = atomicAdd(&next[ed[e]], 1);
        csr[p] = es[e];
    }
}

// ---------------- GATv2 aggregation: one wave per dst node, 2-edge unroll ----------------
__global__ __launch_bounds__(256) void gatv2_agg(
    const float* __restrict__ XL, const float* __restrict__ XR, int ldx,
    const int* __restrict__ csr_src, const int* __restrict__ off,
    const float* __restrict__ att, const float* __restrict__ bias,
    float* __restrict__ out, int n)
{
    int nwg = gridDim.x;
    int q = nwg >> 3;
    int swz = (blockIdx.x & 7) * q + (blockIdx.x >> 3);
    int wid = swz * 4 + (threadIdx.x >> 6);
    int lane = threadIdx.x & 63;
    if (wid >= n) return;
    const int f0 = lane * 8;
    float xr[8], atv[8];
    {
        float4 r0 = *(const float4*)&XR[(size_t)wid * ldx + f0];
        float4 r1 = *(const float4*)&XR[(size_t)wid * ldx + f0 + 4];
        xr[0]=r0.x; xr[1]=r0.y; xr[2]=r0.z; xr[3]=r0.w;
        xr[4]=r1.x; xr[5]=r1.y; xr[6]=r1.z; xr[7]=r1.w;
        float4 t0 = *(const float4*)&att[f0];
        float4 t1 = *(const float4*)&att[f0 + 4];
        atv[0]=t0.x; atv[1]=t0.y; atv[2]=t0.z; atv[3]=t0.w;
        atv[4]=t1.x; atv[5]=t1.y; atv[6]=t1.z; atv[7]=t1.w;
    }

    auto loadrow = [&](int s, float* xl) {
        float4 l0 = *(const float4*)&XL[(size_t)s * ldx + f0];
        float4 l1 = *(const float4*)&XL[(size_t)s * ldx + f0 + 4];
        xl[0]=l0.x; xl[1]=l0.y; xl[2]=l0.z; xl[3]=l0.w;
        xl[4]=l1.x; xl[5]=l1.y; xl[6]=l1.z; xl[7]=l1.w;
    };
    auto logit = [&](const float* xl) {
        float part = 0.f;
#pragma unroll
        for (int j = 0; j < 8; ++j) {
            float v = xl[j] + xr[j];
            v = (v > 0.f) ? v : SLOPE * v;
            part += v * atv[j];
        }
        part += __shfl_xor(part, 1);
        part += __shfl_xor(part, 2);
        part += __shfl_xor(part, 4);
        part += __shfl_xor(part, 8);
        return part;
    };

    // self-loop init (same order as before: self first)
    float xl0[8], acc[8];
    loadrow(wid, xl0);
    float m = logit(xl0), ssum = 1.f;
#pragma unroll
    for (int j = 0; j < 8; ++j) acc[j] = xl0[j];

    auto merge = [&](float part, const float* xl) {
        float mn = fmaxf(m, part);
        float scale = __expf(m - mn);
        float p = __expf(part - mn);
        ssum = ssum * scale + p;
#pragma unroll
        for (int j = 0; j < 8; ++j) acc[j] = acc[j] * scale + p * xl[j];
        m = mn;
    };

    int e0 = off[wid], e1 = off[wid + 1];
    int e = e0;
    for (; e + 1 < e1; e += 2) {
        int s1 = csr_src[e], s2 = csr_src[e + 1];
        float xl1[8], xl2[8];
        loadrow(s1, xl1);
        loadrow(s2, xl2);
        float p1 = logit(xl1);
        float p2 = logit(xl2);
        merge(p1, xl1);
        merge(p2, xl2);
    }
    if (e < e1) {
        int s1 = csr_src[e];
        float xl1[8];
        loadrow(s1, xl1);
        merge(logit(xl1), xl1);
    }

    float inv = 1.f / ssum;
#pragma unroll
    for (int j = 0; j < 8; ++j) {
        float v = acc[j] * inv;
        v += __shfl_xor(v, 16);
        v += __shfl_xor(v, 32);
        if (lane < 16) {
            int c = lane * 8 + j;
            float r = 0.25f * v + bias[c];
            out[(size_t)wid * 128 + c] = fmaxf(r, 0.f);
        }
    }
}

// ---------------- SAGE pooling score (2-edge unroll) ----------------
__global__ __launch_bounds__(256) void sage_score(
    const float* __restrict__ X, const int* __restrict__ csr_src,
    const int* __restrict__ off, const float* __restrict__ Wn,
    const float* __restrict__ Wr, const float* __restrict__ bs,
    float* __restrict__ score, int n)
{
    int wid = (blockIdx.x * blockDim.x + threadIdx.x) >> 6;
    int lane = threadIdx.x & 63;
    if (wid >= n) return;
    int c0 = lane * 2;
    int e0 = off[wid], e1 = off[wid + 1];
    float a0 = 0.f, a1 = 0.f;
    int e = e0;
    for (; e + 1 < e1; e += 2) {
        int s1 = csr_src[e], s2 = csr_src[e + 1];
        float2 v1 = *(const float2*)&X[(size_t)s1 * 128 + c0];
        float2 v2 = *(const float2*)&X[(size_t)s2 * 128 + c0];
        a0 += v1.x + v2.x; a1 += v1.y + v2.y;
    }
    if (e < e1) {
        float2 v = *(const float2*)&X[(size_t)csr_src[e] * 128 + c0];
        a0 += v.x; a1 += v.y;
    }
    float inv = 1.f / fmaxf((float)(e1 - e0), 1.f);
    float2 xv = *(const float2*)&X[(size_t)wid * 128 + c0];
    float part = a0 * inv * Wn[c0] + a1 * inv * Wn[c0 + 1] + xv.x * Wr[c0] + xv.y * Wr[c0 + 1];
#pragma unroll
    for (int sh = 1; sh < 64; sh <<= 1) part += __shfl_xor(part, sh);
    if (lane == 0) score[wid] = part + bs[0];
}

// ---------------- SAGPooling top-k (exact jax.lax.top_k rank) ----------------
__global__ __launch_bounds__(512) void pool_rank(const float* __restrict__ score,
                                                 int npg, int k, int* __restrict__ nmap)
{
    __shared__ float s[512];
    int b = blockIdx.x, t = threadIdx.x;
    const float* sc = score + (size_t)b * npg;
    if (t < npg) s[t] = sc[t];
    __syncthreads();
    if (t < npg) {
        float mine = s[t];
        int rank = 0;
        for (int j = 0; j < npg; ++j) {
            float v = s[j];
            rank += (v > mine) || (v == mine && j < t);
        }
        nmap[(size_t)b * npg + t] = (rank < k) ? (b * k + rank) : -1;
    }
}

// gather + tanh gate; packed fp16 split (optional) + fused global-max readout
__global__ void pool_gather(const float* __restrict__ X, const float* __restrict__ score,
                            const int* __restrict__ nmap,
                            f16* __restrict__ Xh, f16* __restrict__ Xl,
                            unsigned* __restrict__ xgOut, int kk)
{
    int i = blockIdx.x, c = threadIdx.x;  // 128 threads
    int nid = nmap[i];
    if (nid < 0) return;
    float t = tanhf(score[i]);
    float v = X[(size_t)i * 128 + c] * t;
    if (Xh) {
        f16 h = (f16)v;
        size_t off = (((size_t)(nid >> 6) * 16 + (c >> 3)) * 64 + (nid & 63)) * 8 + (c & 7);
        Xh[off] = h;
        Xl[off] = (f16)(v - (float)h);
    }
    int b = nid / kk;
    atomicMax(&xgOut[b * 128 + c], enc_f(v));
}

// ---------------- global max pool (H1 only) ----------------
__global__ void gmp2(const float* __restrict__ X, int npg, int rpb,
                     unsigned* __restrict__ outEnc)
{
    int b = blockIdx.x, q = blockIdx.y, c = threadIdx.x;  // 128 threads
    int r0 = q * rpb, r1 = min(npg, r0 + rpb);
    if (r0 >= r1) return;
    const float* p = X + ((size_t)b * npg + r0) * 128 + c;
    float m = -INFINITY;
    for (int i = r0; i < r1; ++i, p += 128) m = fmaxf(m, *p);
    atomicMax(&outEnc[b * 128 + c], enc_f(m));
}

// ---------------- final: relu((x1+x2+x3) @ Wf + bf) ----------------
__global__ void final_mlp(const unsigned* __restrict__ xg,
                          const float* __restrict__ Wf,
                          const float* __restrict__ bf, float* __restrict__ out)
{
    int b = blockIdx.x, o = threadIdx.x;  // 64 threads
    float acc = bf[o];
    for (int c = 0; c < 128; ++c) {
        int i = b * 128 + c;
        float xv = dec_f(xg[i]) + dec_f(xg[4096 + i]) + dec_f(xg[8192 + i]);
        acc += xv * Wf[c * 64 + o];
    }
    out[b * 64 + o] = fmaxf(acc, 0.f);
}

// ---------------- host orchestration ----------------
static inline size_t alignup(size_t x) { return (x + 255) & ~(size_t)255; }

extern "C" void kernel_launch(void* const* d_in, const int* in_sizes, int n_in,
                              void* d_out, int out_size, void* d_ws, size_t ws_size,
                              hipStream_t stream)
{
    const float* x_feat = (const float*)d_in[0];
    const int*   ei     = (const int*)d_in[1];
    const float* Wl1  = (const float*)d_in[3];
    const float* bl1  = (const float*)d_in[4];
    const float* Wr1  = (const float*)d_in[5];
    const float* br1  = (const float*)d_in[6];
    const float* att1 = (const float*)d_in[7];
    const float* bias1= (const float*)d_in[8];
    const float* Wl2  = (const float*)d_in[9];
    const float* bl2  = (const float*)d_in[10];
    const float* Wr2  = (const float*)d_in[11];
    const float* br2  = (const float*)d_in[12];
    const float* att2 = (const float*)d_in[13];
    const float* bias2= (const float*)d_in[14];
    const float* Wsn  = (const float*)d_in[15];
    const float* Wsr  = (const float*)d_in[16];
    const float* bs   = (const float*)d_in[17];
    const float* Wf   = (const float*)d_in[18];
    const float* bf   = (const float*)d_in[19];
    float* out = (float*)d_out;

    const int* e_src = ei;
    const int* e_dst = ei + ETOT;

    // ---- workspace carve-up ----
    char* ws = (char*)d_ws;
    size_t o = 0;
    auto take = [&](size_t bytes) { size_t r = o; o = alignup(o + bytes); return r; };
    float* C1   = (float*)(ws + take((size_t)NTOT * 1024 * 4));  // XL|XR fp32 (both layers)
    float* H1   = (float*)(ws + take((size_t)NTOT * 128 * 4));
    float* H2   = (float*)(ws + take((size_t)N2 * 128 * 4));
    f16*   Ah1  = (f16*)(ws + take((size_t)NTOT * 512 * 2));
    f16*   Al1  = (f16*)(ws + take((size_t)NTOT * 512 * 2));
    f16*   Wh1  = (f16*)(ws + take((size_t)1024 * 512 * 2));
    f16*   Wo1  = (f16*)(ws + take((size_t)1024 * 512 * 2));
    f16*   Wh2  = (f16*)(ws + take((size_t)1024 * 128 * 2));
    f16*   Wo2  = (f16*)(ws + take((size_t)1024 * 128 * 2));
    f16*   PXh  = (f16*)(ws + take((size_t)N2 * 128 * 2));
    f16*   PXl  = (f16*)(ws + take((size_t)N2 * 128 * 2));
    float* score= (float*)(ws + take((size_t)NTOT * 4));
    int*   nmap = (int*)(ws + take((size_t)NTOT * 4));
    int*   cnt  = (int*)(ws + take((size_t)(NTOT + 1) * 4 + 256));  // ec2 lives at cnt+NTOT+1
    int*   offs = (int*)(ws + take((size_t)(NTOT + 1) * 4));
    int*   nxt  = (int*)(ws + take((size_t)(NTOT + 1) * 4));
    int*   csr1 = (int*)(ws + take((size_t)ETOT * 4));
    int*   es2  = (int*)(ws + take((size_t)ETOT * 4));
    int*   ed2  = (int*)(ws + take((size_t)ETOT * 4));
    int*   csr2 = (int*)(ws + take((size_t)ETOT * 4));
    unsigned* xg = (unsigned*)(ws + take((size_t)3 * NB * 128 * 4));  // x1|x2|x3 encoded
    int* ec2 = cnt + NTOT + 1;
    (void)ws_size; (void)in_sizes; (void)n_in; (void)out_size;

    // ---- prep: split x_feat (packed, coalesced both sides; also zeroes xg & cnt) ----
    split_a<<<dim3(8, NTOT / 64), 256, 0, stream>>>(x_feat, Ah1, Al1, 64, xg, cnt);
    prep_w<<<dim3(512 / 32, 32), 256, 0, stream>>>(Wl1, Wr1, Wh1, Wo1, 512);
    prep_w<<<dim3(128 / 32, 32), 256, 0, stream>>>(Wl2, Wr2, Wh2, Wo2, 128);

    // ---- layer 1 transform: C1 = x @ [Wl1|Wr1] + [bl1|br1]  (split-fp16 MFMA) ----
    gemm_split<<<dim3(8, NTOT / 128), 256, 0, stream>>>(Ah1, Al1, Wh1, Wo1, bl1, br1, C1, NTOT, 512);

    // ---- CSR (by dst) ----
    count_edges<<<ETOT / 256, 256, 0, stream>>>(e_dst, ETOT, cnt);
    scan_excl<<<1, 1024, 0, stream>>>(cnt, NTOT, offs, nxt);
    fill_edges<<<ETOT / 256, 256, 0, stream>>>(e_src, e_dst, ETOT, nxt, csr1);

    // ---- GATv2 layer 1 + relu -> H1; x1 = gmp(H1) ----
    gatv2_agg<<<NTOT / 4, 256, 0, stream>>>(C1, C1 + 512, 1024, csr1, offs, att1, bias1, H1, NTOT);
    gmp2<<<dim3(NB, 8), 128, 0, stream>>>(H1, NPG, 64, xg);

    // ---- SAGE score 1 + pool 1 (packed fp16 split + fused x2 readout) ----
    sage_score<<<NTOT / 4, 256, 0, stream>>>(H1, csr1, offs, Wsn, Wsr, bs, score, NTOT);
    pool_rank<<<NB, 512, 0, stream>>>(score, NPG, K1, nmap);
    pool_gather<<<NTOT, 128, 0, stream>>>(H1, score, nmap, PXh, PXl, xg + 4096, K1);

    // ---- remap + compact edges, CSR2 (one memset covers cnt + ec2) ----
    hipMemsetAsync(cnt, 0, (size_t)(NTOT + 2) * 4, stream);
    remap_edges<<<ETOT / 256, 256, 0, stream>>>(e_src, e_dst, ETOT, nmap, es2, ed2, ec2, cnt);
    scan_excl<<<1, 1024, 0, stream>>>(cnt, N2, offs, nxt);
    fill_edges_dyn<<<ETOT / 256, 256, 0, stream>>>(es2, ed2, ec2, nxt, csr2);

    // ---- layer 2 transform: C1 = PX @ [Wl2|Wr2] + [bl2|br2]  (K=128) ----
    gemm_split<<<dim3(8, N2 / 128), 256, 0, stream>>>(PXh, PXl, Wh2, Wo2, bl2, br2, C1, N2, 128);

    // ---- GATv2 layer 2 + relu -> H2 ----
    gatv2_agg<<<(N2 + 3) / 4, 256, 0, stream>>>(C1, C1 + 512, 1024, csr2, offs, att2, bias2, H2, N2);

    // ---- SAGE score 2 + pool 2 (fused x3 readout; no fp16 emit) ----
    sage_score<<<(N2 + 3) / 4, 256, 0, stream>>>(H2, csr2, offs, Wsn, Wsr, bs, score, N2);
    pool_rank<<<NB, 512, 0, stream>>>(score, K1, K2, nmap);
    pool_gather<<<N2, 128, 0, stream>>>(H2, score, nmap, (f16*)nullptr, (f16*)nullptr, xg + 8192, K2);

    // ---- final MLP ----
    final_mlp<<<NB, 64, 0, stream>>>(xg, Wf, bf, out);
}